// Round 1
// baseline (387.202 us; speedup 1.0000x reference)
//
#include <hip/hip_runtime.h>

// out[b,t] = sum_d x[b,t,d] * stimulus[b,t,d]
// B=8, T=8192, D=768 -> 65536 rows of 768 fp32 (3 KB) per input.
//
// v2: persistent multi-row waves.
//  - 1024 blocks x 256 thr = 4096 waves; each wave owns 16 rows (4 outer
//    iterations x 4 rows). Kills the one-shot-wave churn of v1 (65536 waves).
//  - 4 rows per iteration => 24 outstanding 1 KB global loads per wave
//    (4x the memory-level parallelism of v1).
//  - 4 independent shuffle-reduce chains interleaved => DS-pipe latency of
//    the 6-step reduction is hidden by ILP instead of fully serial.
//  - lane 0 stores one float4 (4 consecutive row sums) instead of a single
//    dword: coalesced, and removes the 2x partial-line write amplification.

constexpr int D4    = 768 / 4;     // 192 float4 per row
constexpr int ROWS  = 8 * 8192;    // 65536
constexpr int RPI   = 4;           // rows per wave per iteration
constexpr int TPB   = 256;
constexpr int BLOCKS = 1024;       // 4096 waves -> 16 rows/wave, exact cover
constexpr int NWAVES = BLOCKS * TPB / 64;

__global__ __launch_bounds__(TPB) void row_dot_kernel(
    const float4* __restrict__ x,
    const float4* __restrict__ y,
    float* __restrict__ out)
{
    const int wave = blockIdx.x * (TPB / 64) + (threadIdx.x >> 6);
    const int lane = threadIdx.x & 63;

    for (int r0 = wave * RPI; r0 < ROWS; r0 += NWAVES * RPI) {
        const size_t b = (size_t)r0 * D4 + lane;

        float acc0 = 0.f, acc1 = 0.f, acc2 = 0.f, acc3 = 0.f;
#pragma unroll
        for (int c = 0; c < 3; ++c) {
            const size_t o = b + c * 64;
            // 8 independent 16B loads per c-step; compiler is free to hoist
            // all 24 across the unrolled loop (no aliasing, __restrict__).
            float4 a0 = x[o];
            float4 a1 = x[o + 1 * D4];
            float4 a2 = x[o + 2 * D4];
            float4 a3 = x[o + 3 * D4];
            float4 s0 = y[o];
            float4 s1 = y[o + 1 * D4];
            float4 s2 = y[o + 2 * D4];
            float4 s3 = y[o + 3 * D4];

            acc0 = fmaf(a0.x, s0.x, acc0); acc0 = fmaf(a0.y, s0.y, acc0);
            acc0 = fmaf(a0.z, s0.z, acc0); acc0 = fmaf(a0.w, s0.w, acc0);
            acc1 = fmaf(a1.x, s1.x, acc1); acc1 = fmaf(a1.y, s1.y, acc1);
            acc1 = fmaf(a1.z, s1.z, acc1); acc1 = fmaf(a1.w, s1.w, acc1);
            acc2 = fmaf(a2.x, s2.x, acc2); acc2 = fmaf(a2.y, s2.y, acc2);
            acc2 = fmaf(a2.z, s2.z, acc2); acc2 = fmaf(a2.w, s2.w, acc2);
            acc3 = fmaf(a3.x, s3.x, acc3); acc3 = fmaf(a3.y, s3.y, acc3);
            acc3 = fmaf(a3.z, s3.z, acc3); acc3 = fmaf(a3.w, s3.w, acc3);
        }

        // 4 interleaved 64-lane reductions (independent chains -> ILP on DS pipe)
#pragma unroll
        for (int off = 32; off > 0; off >>= 1) {
            acc0 += __shfl_down(acc0, off, 64);
            acc1 += __shfl_down(acc1, off, 64);
            acc2 += __shfl_down(acc2, off, 64);
            acc3 += __shfl_down(acc3, off, 64);
        }

        if (lane == 0) {
            // r0 % 4 == 0 -> 16B-aligned coalesced store of 4 row sums
            *reinterpret_cast<float4*>(out + r0) =
                make_float4(acc0, acc1, acc2, acc3);
        }
    }
}

extern "C" void kernel_launch(void* const* d_in, const int* in_sizes, int n_in,
                              void* d_out, int out_size, void* d_ws, size_t ws_size,
                              hipStream_t stream)
{
    const float4* x = (const float4*)d_in[0];
    const float4* y = (const float4*)d_in[1];
    float* out = (float*)d_out;

    row_dot_kernel<<<BLOCKS, TPB, 0, stream>>>(x, y, out);
}

// Round 2
// 386.592 us; speedup vs baseline: 1.0016x; 1.0016x over previous
//
#include <hip/hip_runtime.h>

// out[b,t] = sum_d x[b,t,d] * stimulus[b,t,d]
// B=8, T=8192, D=768 -> 65536 rows of 768 fp32 (3 KB) per input.
//
// v3: max-pressure probe. Same structure as v2 (4 rows/wave/iter, 24 KB of
// loads in flight per wave, interleaved shuffle reductions, float4 store)
// but with the grid-starvation fixed:
//   BLOCKS=2048 x 256 thr = 8192 waves = exactly 32 waves/CU demanded,
//   which is the VGPR-64 residency maximum (8 waves/SIMD). Each wave does
//   2 iterations of 4 rows (exact cover of 65536 rows).
// This is the "full occupancy AND full MLP" corner that neither v1
// (high occ / low MLP) nor v2 (low occ / high MLP) covered. If delivered
// read BW stays pinned at ~3.15 TB/s (= half the 6.29 TB/s copy total),
// the per-direction fabric-cap theory holds and we are at the roofline.

constexpr int D4     = 768 / 4;    // 192 float4 per row
constexpr int ROWS   = 8 * 8192;   // 65536
constexpr int RPI    = 4;          // rows per wave per iteration
constexpr int TPB    = 256;
constexpr int BLOCKS = 2048;       // 8192 waves -> 32 waves/CU demanded
constexpr int NWAVES = BLOCKS * TPB / 64;

__global__ __launch_bounds__(TPB) void row_dot_kernel(
    const float4* __restrict__ x,
    const float4* __restrict__ y,
    float* __restrict__ out)
{
    const int wave = blockIdx.x * (TPB / 64) + (threadIdx.x >> 6);
    const int lane = threadIdx.x & 63;

    // 2 iterations per wave: 8192 waves * 4 rows * 2 = 65536 rows exactly.
    for (int r0 = wave * RPI; r0 < ROWS; r0 += NWAVES * RPI) {
        const size_t b = (size_t)r0 * D4 + lane;

        float acc0 = 0.f, acc1 = 0.f, acc2 = 0.f, acc3 = 0.f;
#pragma unroll
        for (int c = 0; c < 3; ++c) {
            const size_t o = b + c * 64;
            float4 a0 = x[o];
            float4 a1 = x[o + 1 * D4];
            float4 a2 = x[o + 2 * D4];
            float4 a3 = x[o + 3 * D4];
            float4 s0 = y[o];
            float4 s1 = y[o + 1 * D4];
            float4 s2 = y[o + 2 * D4];
            float4 s3 = y[o + 3 * D4];

            acc0 = fmaf(a0.x, s0.x, acc0); acc0 = fmaf(a0.y, s0.y, acc0);
            acc0 = fmaf(a0.z, s0.z, acc0); acc0 = fmaf(a0.w, s0.w, acc0);
            acc1 = fmaf(a1.x, s1.x, acc1); acc1 = fmaf(a1.y, s1.y, acc1);
            acc1 = fmaf(a1.z, s1.z, acc1); acc1 = fmaf(a1.w, s1.w, acc1);
            acc2 = fmaf(a2.x, s2.x, acc2); acc2 = fmaf(a2.y, s2.y, acc2);
            acc2 = fmaf(a2.z, s2.z, acc2); acc2 = fmaf(a2.w, s2.w, acc2);
            acc3 = fmaf(a3.x, s3.x, acc3); acc3 = fmaf(a3.y, s3.y, acc3);
            acc3 = fmaf(a3.z, s3.z, acc3); acc3 = fmaf(a3.w, s3.w, acc3);
        }

        // 4 interleaved 64-lane reductions (independent DS-pipe chains)
#pragma unroll
        for (int off = 32; off > 0; off >>= 1) {
            acc0 += __shfl_down(acc0, off, 64);
            acc1 += __shfl_down(acc1, off, 64);
            acc2 += __shfl_down(acc2, off, 64);
            acc3 += __shfl_down(acc3, off, 64);
        }

        if (lane == 0) {
            // r0 % 4 == 0 -> 16B-aligned coalesced store of 4 row sums
            *reinterpret_cast<float4*>(out + r0) =
                make_float4(acc0, acc1, acc2, acc3);
        }
    }
}

extern "C" void kernel_launch(void* const* d_in, const int* in_sizes, int n_in,
                              void* d_out, int out_size, void* d_ws, size_t ws_size,
                              hipStream_t stream)
{
    const float4* x = (const float4*)d_in[0];
    const float4* y = (const float4*)d_in[1];
    float* out = (float*)d_out;

    row_dot_kernel<<<BLOCKS, TPB, 0, stream>>>(x, y, out);
}